// Round 20
// baseline (100.330 us; speedup 1.0000x reference)
//
#include <hip/hip_runtime.h>
#include <hip/hip_bf16.h>

#define D_MODEL 1024
#define INNER   2048
#define NPROJ   4096   // 2*INNER
#define BSZ     2
#define LSEQ    1024
#define MROWS   (BSZ*LSEQ)  // 2048

#define CHUNK 32
#define WARM  24
#define NCHK  (LSEQ / CHUNK)   // 32

using f32x4    = __attribute__((ext_vector_type(4))) float;
using i32x4    = __attribute__((ext_vector_type(4))) int;
using char16v  = __attribute__((ext_vector_type(16))) char;
typedef unsigned short ushort;
typedef unsigned char uchar;

#define MFMAI8(A,B,Cv) __builtin_amdgcn_mfma_i32_16x16x64_i8(A,B,Cv,0,0,0)

__device__ __forceinline__ void glds16(const void* g, void* l) {
    __builtin_amdgcn_global_load_lds((const __attribute__((address_space(1))) void*)g,
                                     (__attribute__((address_space(3))) void*)l, 16, 0, 0);
}

// ---------------------------------------------------------------------------
// Row-wise two-digit i8 quantization of one row (wave-cooperative) into
// 16x64 FRAGMENT-LINEAR subtiles. x ~ s*(h + l/256), s = rowmax/127.
// ---------------------------------------------------------------------------
template<int K>
__device__ __forceinline__ void quant_row(const float* __restrict__ src_row,
                                          uchar* __restrict__ dh, uchar* __restrict__ dl,
                                          float* __restrict__ ss, int r, int lane) {
    constexpr int CH = K / 1024;
    constexpr int KT64 = K / 64;
    float v[16 * CH];
#pragma unroll
    for (int p = 0; p < 4 * CH; ++p) {
        float4 f = *reinterpret_cast<const float4*>(src_row + lane * 16 * CH + p * 4);
        v[p*4+0] = f.x; v[p*4+1] = f.y; v[p*4+2] = f.z; v[p*4+3] = f.w;
    }
    float mx = 0.f;
#pragma unroll
    for (int j = 0; j < 16 * CH; ++j) mx = fmaxf(mx, fabsf(v[j]));
#pragma unroll
    for (int off = 1; off < 64; off <<= 1) mx = fmaxf(mx, __shfl_xor(mx, off));
    float s1 = fmaxf(mx, 1e-20f) / 127.f;
    if (lane == 0) ss[r] = s1;
    float inv = 1.f / s1;
#pragma unroll
    for (int c = 0; c < CH; ++c) {
        char16v hb, lb;
#pragma unroll
        for (int j = 0; j < 16; ++j) {
            float t = v[c * 16 + j] * inv;
            float h = rintf(t);
            float l = rintf((t - h) * 256.f);
            l = fminf(fmaxf(l, -128.f), 127.f);
            hb[j] = (char)(int)h;
            lb[j] = (char)(int)l;
        }
        int gc = lane * CH + c;
        size_t byte = (((size_t)(r >> 4) * KT64 + (gc >> 2)) * 64
                       + ((gc & 3) << 4) + (r & 15)) * 16;
        *reinterpret_cast<i32x4*>(dh + byte) = *reinterpret_cast<const i32x4*>(&hb);
        *reinterpret_cast<i32x4*>(dl + byte) = *reinterpret_cast<const i32x4*>(&lb);
    }
}

// two-source quant launch (K template). gw < R1 -> S1, else S2.
template<int K>
__global__ __launch_bounds__(256) void quant2src(
    const float* __restrict__ S1, uchar* __restrict__ h1, uchar* __restrict__ l1,
    float* __restrict__ sc1, int R1,
    const float* __restrict__ S2, uchar* __restrict__ h2, uchar* __restrict__ l2,
    float* __restrict__ sc2)
{
    int gw = blockIdx.x * 4 + (threadIdx.x >> 6);
    int lane = threadIdx.x & 63;
    if (gw < R1) quant_row<K>(S1 + (size_t)gw * K, h1, l1, sc1, gw, lane);
    else         quant_row<K>(S2 + (size_t)(gw - R1) * K, h2, l2, sc2, gw - R1, lane);
}

// ---------------------------------------------------------------------------
// Unified i8x3 GEMM body: C[MROWS,NCOL] = A * B^T, pre-quantized two-digit i8.
// BM=BN=128, 4 waves, BK=64, NBUF=2 -> 64KB LDS -> 2 WGs/CU.
// lin is the linear tile index in [0, NTX*(MROWS/128)).
// ---------------------------------------------------------------------------
template<int NCOL, int K, int SPLITK, bool PARTIAL>
__device__ __forceinline__ void gemm_i8_body(
    int lin, int kz,
    const uchar* __restrict__ Ahg, const uchar* __restrict__ Alg, const float* __restrict__ sA,
    const uchar* __restrict__ Bhg, const uchar* __restrict__ Blg, const float* __restrict__ sB,
    float* __restrict__ C0, float* __restrict__ Crest,
    uchar (*Ah)[8192], uchar (*Al)[8192], uchar (*Bh)[8192], uchar (*Bl)[8192])
{
    constexpr int KT64 = K / 64;
    constexpr int NT = KT64 / SPLITK;

    const int tid = threadIdx.x;
    const int wid = tid >> 6, lane = tid & 63;
    const int lm = lane & 15, lk = lane >> 4;

    constexpr int NTX = NCOL / 128;
    constexpr int CPX = (NTX * (MROWS / 128)) / 8;
    int swz = (lin & 7) * CPX + (lin >> 3);
    const int m0 = (swz / NTX) * 128, n0 = (swz % NTX) * 128;
    const int t0 = (SPLITK > 1 ? kz : 0) * NT;
    const int wm = (wid >> 1) * 64, wn = (wid & 1) * 64;

    i32x4 acc1[4][4] = {};
    i32x4 acc2[4][4] = {};

    auto issueB = [&](const uchar* __restrict__ src, uchar* dst, int tg) {
#pragma unroll
        for (int ci = 0; ci < 2; ++ci) {
            int s = wid + ci * 4;
            const uchar* g = src + ((size_t)((n0 >> 4) + s) * KT64 + tg) * 1024 + lane * 16;
            glds16(g, dst + s * 1024);
        }
    };
    auto issueA = [&](const uchar* __restrict__ src, uchar* dst, int tg) {
#pragma unroll
        for (int ci = 0; ci < 2; ++ci) {
            int s = wid + ci * 4;
            const uchar* g = src + ((size_t)((m0 >> 4) + s) * KT64 + tg) * 1024 + lane * 16;
            glds16(g, dst + s * 1024);
        }
    };
    auto stageTile = [&](int tg, int b) {
        issueB(Bhg, &Bh[b][0], tg);
        issueB(Blg, &Bl[b][0], tg);
        issueA(Ahg, &Ah[b][0], tg);
        issueA(Alg, &Al[b][0], tg);
    };

    stageTile(t0, 0);
    asm volatile("s_waitcnt vmcnt(0)" ::: "memory");
    __builtin_amdgcn_s_barrier();

    i32x4 ah[4], bh[4];
#pragma unroll
    for (int i = 0; i < 4; ++i)
        ah[i] = *reinterpret_cast<const i32x4*>(&Ah[0][((wm >> 4) + i) * 1024 + lane * 16]);
#pragma unroll
    for (int q = 0; q < 4; ++q)
        bh[q] = *reinterpret_cast<const i32x4*>(&Bh[0][((wn >> 4) + q) * 1024 + lane * 16]);

    int cur = 0;
    for (int t = 0; t < NT; ++t) {
        int nxt = cur ^ 1;
        const bool pf = (t + 1 < NT);
        i32x4 bl[4], al[4];

        asm volatile("s_waitcnt lgkmcnt(0)" ::: "memory");
        __builtin_amdgcn_sched_barrier(0);
        __builtin_amdgcn_s_setprio(1);
#pragma unroll
        for (int i = 0; i < 4; ++i)
#pragma unroll
            for (int q = 0; q < 4; ++q)
                acc1[i][q] = MFMAI8(ah[i], bh[q], acc1[i][q]);
        __builtin_amdgcn_s_setprio(0);
#pragma unroll
        for (int q = 0; q < 4; ++q)
            bl[q] = *reinterpret_cast<const i32x4*>(&Bl[cur][((wn >> 4) + q) * 1024 + lane * 16]);
        if (pf) issueB(Bhg, &Bh[nxt][0], t0 + t + 1);

        asm volatile("s_waitcnt lgkmcnt(0)" ::: "memory");
        __builtin_amdgcn_sched_barrier(0);
        __builtin_amdgcn_s_setprio(1);
#pragma unroll
        for (int i = 0; i < 4; ++i)
#pragma unroll
            for (int q = 0; q < 4; ++q)
                acc2[i][q] = MFMAI8(ah[i], bl[q], acc2[i][q]);
        __builtin_amdgcn_s_setprio(0);
#pragma unroll
        for (int i = 0; i < 4; ++i)
            al[i] = *reinterpret_cast<const i32x4*>(&Al[cur][((wm >> 4) + i) * 1024 + lane * 16]);
        if (pf) issueB(Blg, &Bl[nxt][0], t0 + t + 1);
        __builtin_amdgcn_s_barrier();

        asm volatile("s_waitcnt lgkmcnt(0)" ::: "memory");
        __builtin_amdgcn_sched_barrier(0);
        __builtin_amdgcn_s_setprio(1);
#pragma unroll
        for (int i = 0; i < 4; ++i)
#pragma unroll
            for (int q = 0; q < 4; ++q)
                acc2[i][q] = MFMAI8(al[i], bh[q], acc2[i][q]);
        __builtin_amdgcn_s_setprio(0);
        if (pf) {
            issueA(Ahg, &Ah[nxt][0], t0 + t + 1);
            issueA(Alg, &Al[nxt][0], t0 + t + 1);
        }
        asm volatile("s_waitcnt vmcnt(0)" ::: "memory");
        __builtin_amdgcn_s_barrier();

        if (t + 1 < NT) {
#pragma unroll
            for (int i = 0; i < 4; ++i)
                ah[i] = *reinterpret_cast<const i32x4*>(&Ah[nxt][((wm >> 4) + i) * 1024 + lane * 16]);
#pragma unroll
            for (int q = 0; q < 4; ++q)
                bh[q] = *reinterpret_cast<const i32x4*>(&Bh[nxt][((wn >> 4) + q) * 1024 + lane * 16]);
        }
        cur = nxt;
    }

    float* C = C0;
    if constexpr (PARTIAL) {
        if (kz != 0) C = Crest + (size_t)(kz - 1) * MROWS * NCOL;
    }
#pragma unroll
    for (int i = 0; i < 4; ++i) {
        int r0 = m0 + wm + i * 16 + lk * 4;
        float4 s4 = *reinterpret_cast<const float4*>(&sA[r0]);
        float sa[4] = {s4.x, s4.y, s4.z, s4.w};
#pragma unroll
        for (int j = 0; j < 4; ++j) {
            int col = n0 + wn + j * 16 + lm;
            float sb = sB[col];
#pragma unroll
            for (int r = 0; r < 4; ++r) {
                float o = sa[r] * sb *
                    ((float)acc1[i][j][r] + (float)acc2[i][j][r] * 0.00390625f);
                C[(size_t)(r0 + r) * NCOL + col] = o;
            }
        }
    }
}

// ---------------------------------------------------------------------------
// GEMM1 fused launch: blocks [0,512) compute C = x * W_in^T (i8x3);
// blocks [512,768) quantize W_out (1024 rows, K=INNER) for GEMM2 — this work
// is independent of gemm1 and runs off the critical path here.
// ---------------------------------------------------------------------------
__global__ __launch_bounds__(256, 2) void gemm1_fused(
    const uchar* __restrict__ Xh, const uchar* __restrict__ Xl, const float* __restrict__ sX,
    const uchar* __restrict__ Wh, const uchar* __restrict__ Wl, const float* __restrict__ sW,
    float* __restrict__ C,
    const float* __restrict__ Wo, uchar* __restrict__ woh, uchar* __restrict__ wol,
    float* __restrict__ sWo)
{
    __shared__ uchar Ah[2][8192], Al[2][8192];
    __shared__ uchar Bh[2][8192], Bl[2][8192];

    int lin = blockIdx.x;
    if (lin >= 512) {
        int gw = (lin - 512) * 4 + (threadIdx.x >> 6);   // W_out row 0..1023
        quant_row<INNER>(Wo + (size_t)gw * INNER, woh, wol, sWo, gw, threadIdx.x & 63);
        return;
    }
    gemm_i8_body<NPROJ, D_MODEL, 1, false>(
        lin, 0, Xh, Xl, sX, Wh, Wl, sW, C, nullptr, Ah, Al, Bh, Bl);
}

// GEMM2 (out_proj) i8x3 split-K launch.
__global__ __launch_bounds__(256, 2) void gemm2_i8(
    const uchar* __restrict__ Yh, const uchar* __restrict__ Yl, const float* __restrict__ sY,
    const uchar* __restrict__ Wh, const uchar* __restrict__ Wl, const float* __restrict__ sW,
    float* __restrict__ C0, float* __restrict__ Crest)
{
    __shared__ uchar Ah[2][8192], Al[2][8192];
    __shared__ uchar Bh[2][8192], Bl[2][8192];
    int lin = blockIdx.y * (D_MODEL / 128) + blockIdx.x;
    gemm_i8_body<D_MODEL, INNER, 4, true>(
        lin, blockIdx.z, Yh, Yl, sY, Wh, Wl, sW, C0, Crest, Ah, Al, Bh, Bl);
}

// out += sum of 3 partials (out already holds partial 0)
__global__ __launch_bounds__(256) void reduce_sk(float* __restrict__ out,
                                                 const float* __restrict__ rest) {
    constexpr size_t MN = (size_t)MROWS * D_MODEL;
    size_t i = ((size_t)blockIdx.x * 256 + threadIdx.x) * 4;
    f32x4 a = *reinterpret_cast<const f32x4*>(&out[i]);
    f32x4 b = *reinterpret_cast<const f32x4*>(&rest[i]);
    f32x4 c = *reinterpret_cast<const f32x4*>(&rest[MN + i]);
    f32x4 d = *reinterpret_cast<const f32x4*>(&rest[2 * MN + i]);
    *reinterpret_cast<f32x4*>(&out[i]) = (a + b) + (c + d);
}

// Chunk-parallel fused conv + sigmoid + scan + gate; emits yg as plain f32.
__global__ __launch_bounds__(256) void scan_kernel(
    const float* __restrict__ xp,
    const float* __restrict__ conv_w, const float* __restrict__ conv_b,
    const float* __restrict__ Aa, const float* __restrict__ Bp, const float* __restrict__ Cp,
    float* __restrict__ yg)
{
    const int NB = INNER / 256;  // 8
    int tid = threadIdx.x;
    int bi = blockIdx.x;
    int b  = bi / (NCHK * NB);
    int r  = bi % (NCHK * NB);
    int ch = r / NB;
    int n  = (r % NB) * 256 + tid;

    float4 w = *reinterpret_cast<const float4*>(&conv_w[n * 4]);
    float cb = conv_b[n];
    float An[16], Bn[16], Cn[16], st[16];
#pragma unroll
    for (int i = 0; i < 16; i += 4) {
        float4 va = *reinterpret_cast<const float4*>(&Aa[n * 16 + i]);
        float4 vb = *reinterpret_cast<const float4*>(&Bp[n * 16 + i]);
        float4 vc = *reinterpret_cast<const float4*>(&Cp[n * 16 + i]);
        An[i]=va.x; An[i+1]=va.y; An[i+2]=va.z; An[i+3]=va.w;
        Bn[i]=vb.x; Bn[i+1]=vb.y; Bn[i+2]=vb.z; Bn[i+3]=vb.w;
        Cn[i]=vc.x; Cn[i+1]=vc.y; Cn[i+2]=vc.z; Cn[i+3]=vc.w;
    }
#pragma unroll
    for (int s = 0; s < 16; ++s) st[s] = 0.f;

    int out0 = ch * CHUNK;
    int lstart = (out0 >= WARM) ? (out0 - WARM) : 0;
    float u0 = 0.f, u1 = 0.f, u2 = 0.f;
    const float* xb = xp + (size_t)b * LSEQ * NPROJ;

    for (int l = lstart; l < out0; l += 8) {
        float uv[8];
#pragma unroll
        for (int i = 0; i < 8; ++i)
            uv[i] = xb[(size_t)(l + i) * NPROJ + 2 * n];
#pragma unroll
        for (int i = 0; i < 8; ++i) {
            float ul = uv[i];
            float xc = cb + w.x * u0 + w.y * u1 + w.z * u2 + w.w * ul;
            u0 = u1; u1 = u2; u2 = ul;
            float d = 1.f / (1.f + __expf(-xc));
            float dxc = d * xc;
#pragma unroll
            for (int s = 0; s < 16; ++s)
                st[s] = (An[s] * d) * st[s] + Bn[s] * dxc;
        }
    }
    for (int lt = 0; lt < CHUNK; lt += 8) {
        float uv[8], gv[8];
#pragma unroll
        for (int i = 0; i < 8; ++i) {
            float2 ug = *reinterpret_cast<const float2*>(
                &xb[(size_t)(out0 + lt + i) * NPROJ + 2 * n]);
            uv[i] = ug.x; gv[i] = ug.y;
        }
#pragma unroll
        for (int i = 0; i < 8; ++i) {
            float ul = uv[i];
            float xc = cb + w.x * u0 + w.y * u1 + w.z * u2 + w.w * ul;
            u0 = u1; u1 = u2; u2 = ul;
            float d = 1.f / (1.f + __expf(-xc));
            float dxc = d * xc;
            float y0 = 0.f, y1 = 0.f, y2 = 0.f, y3 = 0.f;
#pragma unroll
            for (int s = 0; s < 16; s += 4) {
                st[s + 0] = (An[s + 0] * d) * st[s + 0] + Bn[s + 0] * dxc;
                st[s + 1] = (An[s + 1] * d) * st[s + 1] + Bn[s + 1] * dxc;
                st[s + 2] = (An[s + 2] * d) * st[s + 2] + Bn[s + 2] * dxc;
                st[s + 3] = (An[s + 3] * d) * st[s + 3] + Bn[s + 3] * dxc;
                y0 += st[s + 0] * Cn[s + 0];
                y1 += st[s + 1] * Cn[s + 1];
                y2 += st[s + 2] * Cn[s + 2];
                y3 += st[s + 3] * Cn[s + 3];
            }
            float y = (y0 + y1) + (y2 + y3);
            float g = 1.f / (1.f + __expf(-gv[i]));
            int R = b * LSEQ + out0 + lt + i;
            yg[(size_t)R * INNER + n] = y * g;
        }
    }
}

extern "C" void kernel_launch(void* const* d_in, const int* in_sizes, int n_in,
                              void* d_out, int out_size, void* d_ws, size_t ws_size,
                              hipStream_t stream) {
    const float* x      = (const float*)d_in[0];
    const float* W_in   = (const float*)d_in[1];
    const float* conv_w = (const float*)d_in[2];
    const float* conv_b = (const float*)d_in[3];
    const float* A      = (const float*)d_in[4];
    const float* Bp     = (const float*)d_in[5];
    const float* Cp     = (const float*)d_in[6];
    const float* W_out  = (const float*)d_in[8];
    float* out = (float*)d_out;

    char* ws = (char*)d_ws;
    float* xp    = (float*)ws;                       // [0,32M) gemm1 out / scan in
    uchar* Wh8   = (uchar*)(ws + (32u << 20));       // [32,36M) W_in i8 hi
    uchar* Wl8   = (uchar*)(ws + (36u << 20));       // [36,40M) W_in i8 lo
    float* sW    = (float*)(ws + (40u << 20));       // 16KB
    float* yg    = (float*)(ws + (32u << 20));       // [32,48M) scan out (after gemm1)
    uchar* ygh8  = (uchar*)ws;                       // [0,4M)  (xp dead after scan)
    uchar* ygl8  = (uchar*)(ws + (4u << 20));        // [4,8M)
    float* Prest = (float*)(ws + (8u << 20));        // [8,32M) split-K partials 1..3
    uchar* woh8  = (uchar*)(ws + (48u << 20));       // [48,50M)
    uchar* wol8  = (uchar*)(ws + (50u << 20));       // [50,52M)
    float* sY    = (float*)(ws + (52u << 20));       // 8KB
    float* sWo   = (float*)(ws + (52u << 20) + (16u << 10));  // 4KB
    uchar* xh8 = (uchar*)d_out;                      // [0,2M)  x i8 in d_out
    uchar* xl8 = xh8 + (2u << 20);                   // [2,4M)
    float* sX  = (float*)(xh8 + (4u << 20));         // 8KB

    dim3 blk(256);
    quant2src<D_MODEL><<<dim3((NPROJ + MROWS) / 4), blk, 0, stream>>>(
        W_in, Wh8, Wl8, sW, NPROJ, x, xh8, xl8, sX);
    gemm1_fused<<<dim3(512 + 256), blk, 0, stream>>>(
        xh8, xl8, sX, Wh8, Wl8, sW, xp, W_out, woh8, wol8, sWo);
    scan_kernel<<<dim3(BSZ * NCHK * (INNER / 256)), blk, 0, stream>>>(
        xp, conv_w, conv_b, A, Bp, Cp, yg);
    quant2src<INNER><<<dim3(MROWS / 4), blk, 0, stream>>>(
        yg, ygh8, ygl8, sY, MROWS, nullptr, nullptr, nullptr, nullptr);
    gemm2_i8<<<dim3(8, 16, 4), blk, 0, stream>>>(
        ygh8, ygl8, sY, woh8, wol8, sWo, out, Prest);
    reduce_sk<<<dim3((MROWS * D_MODEL / 4) / 256), blk, 0, stream>>>(out, Prest);
}

// Round 21
// 99.518 us; speedup vs baseline: 1.0082x; 1.0082x over previous
//
#include <hip/hip_runtime.h>
#include <hip/hip_bf16.h>

#define D_MODEL 1024
#define INNER   2048
#define NPROJ   4096   // 2*INNER
#define BSZ     2
#define LSEQ    1024
#define MROWS   (BSZ*LSEQ)  // 2048

#define CHUNK 32
#define WARM  24
#define NCHK  (LSEQ / CHUNK)   // 32

using f32x4    = __attribute__((ext_vector_type(4))) float;
using i32x4    = __attribute__((ext_vector_type(4))) int;
using char16v  = __attribute__((ext_vector_type(16))) char;
typedef unsigned short ushort;
typedef unsigned char uchar;

#define MFMAI8(A,B,Cv) __builtin_amdgcn_mfma_i32_16x16x64_i8(A,B,Cv,0,0,0)

__device__ __forceinline__ void glds16(const void* g, void* l) {
    __builtin_amdgcn_global_load_lds((const __attribute__((address_space(1))) void*)g,
                                     (__attribute__((address_space(3))) void*)l, 16, 0, 0);
}

// ---------------------------------------------------------------------------
// Row-wise two-digit i8 quantization into 16x64 FRAGMENT-LINEAR subtiles.
// x ~ s*(h + l/256), s = rowmax/127. Subtile (rt,kt) = 16 rows x 64 k;
// lane holds 16 contiguous k-bytes per chunk. Two sources per launch.
// ---------------------------------------------------------------------------
template<int K>
__global__ __launch_bounds__(256) void quant2src(
    const float* __restrict__ S1, uchar* __restrict__ h1, uchar* __restrict__ l1,
    float* __restrict__ sc1, int R1,
    const float* __restrict__ S2, uchar* __restrict__ h2, uchar* __restrict__ l2,
    float* __restrict__ sc2)
{
    constexpr int CH = K / 1024;     // 16-elem chunks per lane
    constexpr int KT64 = K / 64;
    int gw = blockIdx.x * 4 + (threadIdx.x >> 6);
    int lane = threadIdx.x & 63;
    const float* src; uchar *dh, *dl; float* ss; int r;
    if (gw < R1) { r = gw;      src = S1 + (size_t)r * K; dh = h1; dl = l1; ss = sc1; }
    else         { r = gw - R1; src = S2 + (size_t)r * K; dh = h2; dl = l2; ss = sc2; }

    float v[16 * CH];
#pragma unroll
    for (int p = 0; p < 4 * CH; ++p) {
        float4 f = *reinterpret_cast<const float4*>(src + lane * 16 * CH + p * 4);
        v[p*4+0] = f.x; v[p*4+1] = f.y; v[p*4+2] = f.z; v[p*4+3] = f.w;
    }
    float mx = 0.f;
#pragma unroll
    for (int j = 0; j < 16 * CH; ++j) mx = fmaxf(mx, fabsf(v[j]));
#pragma unroll
    for (int off = 1; off < 64; off <<= 1) mx = fmaxf(mx, __shfl_xor(mx, off));
    float s1 = fmaxf(mx, 1e-20f) / 127.f;
    if (lane == 0) ss[r] = s1;
    float inv = 1.f / s1;
#pragma unroll
    for (int c = 0; c < CH; ++c) {
        char16v hb, lb;
#pragma unroll
        for (int j = 0; j < 16; ++j) {
            float t = v[c * 16 + j] * inv;
            float h = rintf(t);
            float l = rintf((t - h) * 256.f);
            l = fminf(fmaxf(l, -128.f), 127.f);
            hb[j] = (char)(int)h;
            lb[j] = (char)(int)l;
        }
        int gc = lane * CH + c;
        size_t byte = (((size_t)(r >> 4) * KT64 + (gc >> 2)) * 64
                       + ((gc & 3) << 4) + (r & 15)) * 16;
        *reinterpret_cast<i32x4*>(dh + byte) = *reinterpret_cast<const i32x4*>(&hb);
        *reinterpret_cast<i32x4*>(dl + byte) = *reinterpret_cast<const i32x4*>(&lb);
    }
}

// ---------------------------------------------------------------------------
// Unified i8x3 GEMM: C[MROWS,NCOL] = A * B^T, A/B pre-quantized two-digit i8.
// BM=BN=128, 4 waves (2Mx2N, wave 64x64), BK=64, NBUF=2 -> 64KB LDS ->
// 2 WGs/CU (co-resident WGs hide each other's tile-boundary drains, m114).
// Per tile: R1{8 MFMA hh; read bl; issue Bh'} R2{8 MFMA hl; read al; issue
// Bl'} BAR R3{8 MFMA lh; issue A'; vmcnt(0)} BAR R4{read next ah,bh}.
// C = sA[r]*sB[c]*(acc1 + acc2/256). SPLITK>1: kz>0 writes Crest partials.
// ---------------------------------------------------------------------------
template<int NCOL, int K, int SPLITK, bool PARTIAL>
__global__ __launch_bounds__(256, 2) void gemm_i8(
    const uchar* __restrict__ Ahg, const uchar* __restrict__ Alg, const float* __restrict__ sA,
    const uchar* __restrict__ Bhg, const uchar* __restrict__ Blg, const float* __restrict__ sB,
    float* __restrict__ C0, float* __restrict__ Crest)
{
    constexpr int KT64 = K / 64;
    constexpr int NT = KT64 / SPLITK;
    __shared__ uchar Ah[2][8192], Al[2][8192];   // 128x64 i8
    __shared__ uchar Bh[2][8192], Bl[2][8192];

    const int tid = threadIdx.x;
    const int wid = tid >> 6, lane = tid & 63;
    const int lm = lane & 15, lk = lane >> 4;

    constexpr int NTX = NCOL / 128;
    constexpr int CPX = (NTX * (MROWS / 128)) / 8;
    int lin = blockIdx.y * NTX + blockIdx.x;
    int swz = (lin & 7) * CPX + (lin >> 3);
    const int m0 = (swz / NTX) * 128, n0 = (swz % NTX) * 128;
    const int t0 = (SPLITK > 1 ? blockIdx.z : 0) * NT;
    const int wm = (wid >> 1) * 64, wn = (wid & 1) * 64;

    i32x4 acc1[4][4] = {};
    i32x4 acc2[4][4] = {};

    auto issueB = [&](const uchar* __restrict__ src, uchar* dst, int tg) {
#pragma unroll
        for (int ci = 0; ci < 2; ++ci) {
            int s = wid + ci * 4;
            const uchar* g = src + ((size_t)((n0 >> 4) + s) * KT64 + tg) * 1024 + lane * 16;
            glds16(g, dst + s * 1024);
        }
    };
    auto issueA = [&](const uchar* __restrict__ src, uchar* dst, int tg) {
#pragma unroll
        for (int ci = 0; ci < 2; ++ci) {
            int s = wid + ci * 4;
            const uchar* g = src + ((size_t)((m0 >> 4) + s) * KT64 + tg) * 1024 + lane * 16;
            glds16(g, dst + s * 1024);
        }
    };
    auto stageTile = [&](int tg, int b) {
        issueB(Bhg, &Bh[b][0], tg);
        issueB(Blg, &Bl[b][0], tg);
        issueA(Ahg, &Ah[b][0], tg);
        issueA(Alg, &Al[b][0], tg);
    };

    stageTile(t0, 0);
    asm volatile("s_waitcnt vmcnt(0)" ::: "memory");
    __builtin_amdgcn_s_barrier();

    i32x4 ah[4], bh[4];
#pragma unroll
    for (int i = 0; i < 4; ++i)
        ah[i] = *reinterpret_cast<const i32x4*>(&Ah[0][((wm >> 4) + i) * 1024 + lane * 16]);
#pragma unroll
    for (int q = 0; q < 4; ++q)
        bh[q] = *reinterpret_cast<const i32x4*>(&Bh[0][((wn >> 4) + q) * 1024 + lane * 16]);

    int cur = 0;
    for (int t = 0; t < NT; ++t) {
        int nxt = cur ^ 1;
        const bool pf = (t + 1 < NT);
        i32x4 bl[4], al[4];

        // ---- R1: hh MFMA -> acc1; read bl(cur); issue Bh(t+1) ----
        asm volatile("s_waitcnt lgkmcnt(0)" ::: "memory");
        __builtin_amdgcn_sched_barrier(0);
        __builtin_amdgcn_s_setprio(1);
#pragma unroll
        for (int i = 0; i < 4; ++i)
#pragma unroll
            for (int q = 0; q < 4; ++q)
                acc1[i][q] = MFMAI8(ah[i], bh[q], acc1[i][q]);
        __builtin_amdgcn_s_setprio(0);
#pragma unroll
        for (int q = 0; q < 4; ++q)
            bl[q] = *reinterpret_cast<const i32x4*>(&Bl[cur][((wn >> 4) + q) * 1024 + lane * 16]);
        if (pf) issueB(Bhg, &Bh[nxt][0], t0 + t + 1);

        // ---- R2: hl MFMA -> acc2; read al(cur); issue Bl(t+1) ----
        asm volatile("s_waitcnt lgkmcnt(0)" ::: "memory");
        __builtin_amdgcn_sched_barrier(0);
        __builtin_amdgcn_s_setprio(1);
#pragma unroll
        for (int i = 0; i < 4; ++i)
#pragma unroll
            for (int q = 0; q < 4; ++q)
                acc2[i][q] = MFMAI8(ah[i], bl[q], acc2[i][q]);
        __builtin_amdgcn_s_setprio(0);
#pragma unroll
        for (int i = 0; i < 4; ++i)
            al[i] = *reinterpret_cast<const i32x4*>(&Al[cur][((wm >> 4) + i) * 1024 + lane * 16]);
        if (pf) issueB(Blg, &Bl[nxt][0], t0 + t + 1);
        __builtin_amdgcn_s_barrier();

        // ---- R3: lh MFMA -> acc2; issue A(t+1); drain ----
        asm volatile("s_waitcnt lgkmcnt(0)" ::: "memory");
        __builtin_amdgcn_sched_barrier(0);
        __builtin_amdgcn_s_setprio(1);
#pragma unroll
        for (int i = 0; i < 4; ++i)
#pragma unroll
            for (int q = 0; q < 4; ++q)
                acc2[i][q] = MFMAI8(al[i], bh[q], acc2[i][q]);
        __builtin_amdgcn_s_setprio(0);
        if (pf) {
            issueA(Ahg, &Ah[nxt][0], t0 + t + 1);
            issueA(Alg, &Al[nxt][0], t0 + t + 1);
        }
        asm volatile("s_waitcnt vmcnt(0)" ::: "memory");
        __builtin_amdgcn_s_barrier();

        // ---- R4: read next tile's hh frags ----
        if (t + 1 < NT) {
#pragma unroll
            for (int i = 0; i < 4; ++i)
                ah[i] = *reinterpret_cast<const i32x4*>(&Ah[nxt][((wm >> 4) + i) * 1024 + lane * 16]);
#pragma unroll
            for (int q = 0; q < 4; ++q)
                bh[q] = *reinterpret_cast<const i32x4*>(&Bh[nxt][((wn >> 4) + q) * 1024 + lane * 16]);
        }
        cur = nxt;
    }

    float* C = C0;
    if constexpr (PARTIAL) {
        int kz = blockIdx.z;
        if (kz != 0) C = Crest + (size_t)(kz - 1) * MROWS * NCOL;
    }
#pragma unroll
    for (int i = 0; i < 4; ++i) {
        int r0 = m0 + wm + i * 16 + lk * 4;
        float4 s4 = *reinterpret_cast<const float4*>(&sA[r0]);
        float sa[4] = {s4.x, s4.y, s4.z, s4.w};
#pragma unroll
        for (int j = 0; j < 4; ++j) {
            int col = n0 + wn + j * 16 + lm;
            float sb = sB[col];
#pragma unroll
            for (int r = 0; r < 4; ++r) {
                float o = sa[r] * sb *
                    ((float)acc1[i][j][r] + (float)acc2[i][j][r] * 0.00390625f);
                C[(size_t)(r0 + r) * NCOL + col] = o;
            }
        }
    }
}

// out += sum of 3 partials (out already holds partial 0)
__global__ __launch_bounds__(256) void reduce_sk(float* __restrict__ out,
                                                 const float* __restrict__ rest) {
    constexpr size_t MN = (size_t)MROWS * D_MODEL;
    size_t i = ((size_t)blockIdx.x * 256 + threadIdx.x) * 4;
    f32x4 a = *reinterpret_cast<const f32x4*>(&out[i]);
    f32x4 b = *reinterpret_cast<const f32x4*>(&rest[i]);
    f32x4 c = *reinterpret_cast<const f32x4*>(&rest[MN + i]);
    f32x4 d = *reinterpret_cast<const f32x4*>(&rest[2 * MN + i]);
    *reinterpret_cast<f32x4*>(&out[i]) = (a + b) + (c + d);
}

// Chunk-parallel fused conv + sigmoid + scan + gate; emits yg as plain f32
// row-major (R, n) for the quantization pass.
__global__ __launch_bounds__(256) void scan_kernel(
    const float* __restrict__ xp,
    const float* __restrict__ conv_w, const float* __restrict__ conv_b,
    const float* __restrict__ Aa, const float* __restrict__ Bp, const float* __restrict__ Cp,
    float* __restrict__ yg)
{
    const int NB = INNER / 256;  // 8
    int tid = threadIdx.x;
    int bi = blockIdx.x;
    int b  = bi / (NCHK * NB);
    int r  = bi % (NCHK * NB);
    int ch = r / NB;
    int n  = (r % NB) * 256 + tid;

    float4 w = *reinterpret_cast<const float4*>(&conv_w[n * 4]);
    float cb = conv_b[n];
    float An[16], Bn[16], Cn[16], st[16];
#pragma unroll
    for (int i = 0; i < 16; i += 4) {
        float4 va = *reinterpret_cast<const float4*>(&Aa[n * 16 + i]);
        float4 vb = *reinterpret_cast<const float4*>(&Bp[n * 16 + i]);
        float4 vc = *reinterpret_cast<const float4*>(&Cp[n * 16 + i]);
        An[i]=va.x; An[i+1]=va.y; An[i+2]=va.z; An[i+3]=va.w;
        Bn[i]=vb.x; Bn[i+1]=vb.y; Bn[i+2]=vb.z; Bn[i+3]=vb.w;
        Cn[i]=vc.x; Cn[i+1]=vc.y; Cn[i+2]=vc.z; Cn[i+3]=vc.w;
    }
#pragma unroll
    for (int s = 0; s < 16; ++s) st[s] = 0.f;

    int out0 = ch * CHUNK;
    int lstart = (out0 >= WARM) ? (out0 - WARM) : 0;
    float u0 = 0.f, u1 = 0.f, u2 = 0.f;
    const float* xb = xp + (size_t)b * LSEQ * NPROJ;

    for (int l = lstart; l < out0; l += 8) {
        float uv[8];
#pragma unroll
        for (int i = 0; i < 8; ++i)
            uv[i] = xb[(size_t)(l + i) * NPROJ + 2 * n];
#pragma unroll
        for (int i = 0; i < 8; ++i) {
            float ul = uv[i];
            float xc = cb + w.x * u0 + w.y * u1 + w.z * u2 + w.w * ul;
            u0 = u1; u1 = u2; u2 = ul;
            float d = 1.f / (1.f + __expf(-xc));
            float dxc = d * xc;
#pragma unroll
            for (int s = 0; s < 16; ++s)
                st[s] = (An[s] * d) * st[s] + Bn[s] * dxc;
        }
    }
    for (int lt = 0; lt < CHUNK; lt += 8) {
        float uv[8], gv[8];
#pragma unroll
        for (int i = 0; i < 8; ++i) {
            float2 ug = *reinterpret_cast<const float2*>(
                &xb[(size_t)(out0 + lt + i) * NPROJ + 2 * n]);
            uv[i] = ug.x; gv[i] = ug.y;
        }
#pragma unroll
        for (int i = 0; i < 8; ++i) {
            float ul = uv[i];
            float xc = cb + w.x * u0 + w.y * u1 + w.z * u2 + w.w * ul;
            u0 = u1; u1 = u2; u2 = ul;
            float d = 1.f / (1.f + __expf(-xc));
            float dxc = d * xc;
            float y0 = 0.f, y1 = 0.f, y2 = 0.f, y3 = 0.f;
#pragma unroll
            for (int s = 0; s < 16; s += 4) {
                st[s + 0] = (An[s + 0] * d) * st[s + 0] + Bn[s + 0] * dxc;
                st[s + 1] = (An[s + 1] * d) * st[s + 1] + Bn[s + 1] * dxc;
                st[s + 2] = (An[s + 2] * d) * st[s + 2] + Bn[s + 2] * dxc;
                st[s + 3] = (An[s + 3] * d) * st[s + 3] + Bn[s + 3] * dxc;
                y0 += st[s + 0] * Cn[s + 0];
                y1 += st[s + 1] * Cn[s + 1];
                y2 += st[s + 2] * Cn[s + 2];
                y3 += st[s + 3] * Cn[s + 3];
            }
            float y = (y0 + y1) + (y2 + y3);
            float g = 1.f / (1.f + __expf(-gv[i]));
            int R = b * LSEQ + out0 + lt + i;
            yg[(size_t)R * INNER + n] = y * g;
        }
    }
}

extern "C" void kernel_launch(void* const* d_in, const int* in_sizes, int n_in,
                              void* d_out, int out_size, void* d_ws, size_t ws_size,
                              hipStream_t stream) {
    const float* x      = (const float*)d_in[0];
    const float* W_in   = (const float*)d_in[1];
    const float* conv_w = (const float*)d_in[2];
    const float* conv_b = (const float*)d_in[3];
    const float* A      = (const float*)d_in[4];
    const float* Bp     = (const float*)d_in[5];
    const float* Cp     = (const float*)d_in[6];
    const float* W_out  = (const float*)d_in[8];
    float* out = (float*)d_out;

    char* ws = (char*)d_ws;
    float* xp    = (float*)ws;                       // [0,32M) gemm1 out / scan in
    uchar* Wh8   = (uchar*)(ws + (32u << 20));       // [32,36M) W_in i8 hi
    uchar* Wl8   = (uchar*)(ws + (36u << 20));       // [36,40M) W_in i8 lo
    float* sW    = (float*)(ws + (40u << 20));       // 16KB
    float* yg    = (float*)(ws + (32u << 20));       // [32,48M) scan out (after gemm1)
    uchar* ygh8  = (uchar*)ws;                       // [0,4M)  (xp dead after scan)
    uchar* ygl8  = (uchar*)(ws + (4u << 20));        // [4,8M)
    float* Prest = (float*)(ws + (8u << 20));        // [8,32M) split-K partials 1..3
    uchar* woh8  = (uchar*)(ws + (48u << 20));       // [48,50M)
    uchar* wol8  = (uchar*)(ws + (50u << 20));       // [50,52M)
    float* sY    = (float*)(ws + (52u << 20));       // 8KB
    float* sWo   = (float*)(ws + (52u << 20) + (16u << 10));  // 4KB
    uchar* xh8 = (uchar*)d_out;                      // [0,2M)  x i8 in d_out
    uchar* xl8 = xh8 + (2u << 20);                   // [2,4M)
    float* sX  = (float*)(xh8 + (4u << 20));         // 8KB

    dim3 blk(256);
    quant2src<D_MODEL><<<dim3((NPROJ + MROWS) / 4), blk, 0, stream>>>(
        W_in, Wh8, Wl8, sW, NPROJ, x, xh8, xl8, sX);
    gemm_i8<NPROJ, D_MODEL, 1, false><<<dim3(32, 16), blk, 0, stream>>>(
        xh8, xl8, sX, Wh8, Wl8, sW, xp, nullptr);
    scan_kernel<<<dim3(BSZ * NCHK * (INNER / 256)), blk, 0, stream>>>(
        xp, conv_w, conv_b, A, Bp, Cp, yg);
    quant2src<INNER><<<dim3((MROWS + D_MODEL) / 4), blk, 0, stream>>>(
        yg, ygh8, ygl8, sY, MROWS, W_out, woh8, wol8, sWo);
    gemm_i8<D_MODEL, INNER, 4, true><<<dim3(8, 16, 4), blk, 0, stream>>>(
        ygh8, ygl8, sY, woh8, wol8, sWo, out, Prest);
    reduce_sk<<<dim3((MROWS * D_MODEL / 4) / 256), blk, 0, stream>>>(out, Prest);
}